// Round 8
// baseline (279.816 us; speedup 1.0000x reference)
//
#include <hip/hip_runtime.h>
#include <hip/hip_fp16.h>
#include <math.h>

// n=16, C=512, c4=128, qk=16, H=W=32, L=1024. fp32 in/out.
// 8 dispatches: prep(fused) -> feat -> qk2 -> pvmm2 -> basecor -> fattn -> convmm -> final.
//
// ws layout (float offsets):
#define OFF_COR   0u          // cor   [16][512][9] f32
#define OFF_PVH   2097152u    // pvh   [16][128][1024] f16
#define OFF_Y     3145728u    // yh    [16][512][1024] f16  (UNION: xT f16 [16][1024][512], dead before convmm)
#define OFF_CATP  11534336u   // catT_p[16][1156][256] bf16 (pixel-major, 34x34 zero-padded)
#define OFF_QH    15085568u   // qh    [2][16][1024][16] f16
#define OFF_KH    15347712u   // kh    [2][16][1024][16] f16
#define OFF_POOL  16134144u   // pool  [16][512][20] f32
#define OFF_FEAT  16297984u   // feat  [16][128][20] f32
#define OFF_AW    16338944u   // Aw    [512][2304] bf16 (k = (ky*3+kx)*256 + (ic-128))
#define OFF_MEANS 17223680u   // means [16][128] f32 (RAW SUM over l; /1024 in basecor)
#define OFF_STAT  17225728u   // stats [1024] f32: [0:512)=sum(y), [512:1024)=sum(y^2)
#define OFF_VWH   17226752u   // vwh   [128][512] f16

typedef __bf16 bf16x8 __attribute__((ext_vector_type(8)));
typedef _Float16 f16x8 __attribute__((ext_vector_type(8)));
typedef _Float16 f16x4 __attribute__((ext_vector_type(4)));
typedef float f32x4 __attribute__((ext_vector_type(4)));

__device__ __forceinline__ unsigned short f2bf(float f) {
  unsigned int u = __float_as_uint(f);
  unsigned int r = u + 0x7fff + ((u >> 16) & 1);   // RNE
  return (unsigned short)(r >> 16);
}

__device__ __forceinline__ unsigned short f2h(float f) {
  union { _Float16 h; unsigned short u; } cv;
  cv.h = (_Float16)f;
  return cv.u;
}

__device__ __forceinline__ void gload_lds16(const void* g, void* l) {
  __builtin_amdgcn_global_load_lds(
      (const __attribute__((address_space(1))) unsigned int*)g,
      (__attribute__((address_space(3))) unsigned int*)l, 16, 0, 0);
}

// =============== prep: pool | xcast | vwcast | wcast | fillcat | zero ===============
// blocks [0,8192): pool; [8192,10240): xcast; [10240,10496): vwcast;
// [10496,11008): wcast; [11008,12064): fillcat (2 border rows each); [12064]: zero.
__global__ __launch_bounds__(256) void prep_kernel(const float* __restrict__ x,
                                                   const float* __restrict__ vw,
                                                   const float* __restrict__ fw,
                                                   float* __restrict__ pool,
                                                   unsigned short* __restrict__ xT,
                                                   unsigned short* __restrict__ vwh,
                                                   unsigned short* __restrict__ Aw,
                                                   unsigned short* __restrict__ catp,
                                                   float* __restrict__ stats,
                                                   float* __restrict__ means) {
  int b = blockIdx.x;
  int t = threadIdx.x;
  __shared__ float smem[64 * 65];
  if (b < 8192) {
    // ---- pool: pooled4 (8x8 blocks) + pooled2 derived; b = n*512 + c ----
    const float4* xp = (const float4*)(x + (size_t)b * 1024);
    float4 v = xp[t];
    float s4 = v.x + v.y + v.z + v.w;
    float* sm = smem;          // 256
    float* p4s = smem + 256;   // 16
    sm[t] = s4;
    __syncthreads();
    if (t < 16) {
      int br = t >> 2, bc = t & 3;
      float s = 0.f;
#pragma unroll
      for (int rr = 0; rr < 8; ++rr) {
        int base = br * 64 + rr * 8 + bc * 2;
        s += sm[base] + sm[base + 1];
      }
      s *= (1.f / 64.f);
      p4s[t] = s;
      pool[(size_t)b * 20 + t] = s;
    }
    __syncthreads();
    if (t < 4) {
      int i2 = t >> 1, j2 = t & 1;
      float s = (p4s[(2*i2)*4 + 2*j2]     + p4s[(2*i2)*4 + 2*j2 + 1] +
                 p4s[(2*i2+1)*4 + 2*j2]   + p4s[(2*i2+1)*4 + 2*j2 + 1]) * 0.25f;
      pool[(size_t)b * 20 + 16 + t] = s;
    }
  } else if (b < 10240) {
    // ---- xcast: xT[n][l][c] = f16(x[n][c][l]) ----
    int u = b - 8192;
    int lt = u & 15, ct = (u >> 4) & 7, n = u >> 7;
    int l0 = lt * 64, c0 = ct * 64;
#pragma unroll
    for (int i = 0; i < 16; ++i) {
      int idx = t + 256 * i;
      int c = idx >> 6, l = idx & 63;
      smem[c * 65 + l] = x[((size_t)n * 512 + c0 + c) * 1024 + l0 + l];
    }
    __syncthreads();
#pragma unroll
    for (int i = 0; i < 16; ++i) {
      int idx = t + 256 * i;
      int l = idx >> 6, c = idx & 63;
      xT[((size_t)n * 1024 + l0 + l) * 512 + c0 + c] = f2h(smem[c * 65 + l]);
    }
  } else if (b < 10496) {
    // ---- vwcast ----
    int i = (b - 10240) * 256 + t;
    vwh[i] = f2h(vw[i]);
  } else if (b < 11008) {
    // ---- wcast: Aw[oc][seg*256 + (ic-128)] ----
    int oc = b - 10496;
    for (int j = t; j < 2304; j += 256) {
      int seg = j >> 8, ic2 = j & 255;
      Aw[(size_t)oc * 2304 + j] = f2bf(fw[(size_t)oc * 3456 + (128 + ic2) * 9 + seg]);
    }
  } else if (b < 12064) {
    // ---- fillcat: zero 2 border rows per block (2112 rows total) ----
    int rr = (b - 11008) * 2 + (t >> 7);
    int n = rr / 132, e = rr % 132;
    int py, px;
    if (e < 34)       { py = 0;           px = e; }
    else if (e < 68)  { py = 33;          px = e - 34; }
    else if (e < 100) { py = e - 68 + 1;  px = 0; }
    else              { py = e - 100 + 1; px = 33; }
    unsigned int* row = (unsigned int*)(catp + ((size_t)n * 1156 + py * 34 + px) * 256);
    row[t & 127] = 0u;
  } else {
    // ---- zero stats (1024) + means (2048) ----
    for (int i = t; i < 3072; i += 256) {
      if (i < 1024) stats[i] = 0.f;
      else means[i - 1024] = 0.f;
    }
  }
}

// ---------------- feat = rce_w[i] @ pooled_i + rce_b[i] (scales sz=2,4) ----------------
__global__ __launch_bounds__(64) void feat_kernel(const float* __restrict__ pool,
                                                  const float* __restrict__ rce_w,
                                                  const float* __restrict__ rce_b,
                                                  float* __restrict__ feat) {
  int o = blockIdx.x, n = blockIdx.y, t = threadIdx.x;
  float part[20];
#pragma unroll
  for (int j = 0; j < 20; ++j) part[j] = 0.f;
  for (int c = t; c < 512; c += 64) {
    const float* pl = pool + ((size_t)n * 512 + c) * 20;
    float w2 = rce_w[(size_t)(128 + o) * 512 + c];
    float w4 = rce_w[(size_t)(256 + o) * 512 + c];
#pragma unroll
    for (int j = 0; j < 4; ++j)  part[j]     += w2 * pl[16 + j];
#pragma unroll
    for (int j = 0; j < 16; ++j) part[4 + j] += w4 * pl[j];
  }
  __shared__ float red[64][20];
#pragma unroll
  for (int j = 0; j < 20; ++j) red[t][j] = part[j];
  __syncthreads();
  if (t < 20) {
    float s = 0.f;
    for (int i = 0; i < 64; ++i) s += red[i][t];
    s += (t < 4) ? rce_b[128 + o] : rce_b[256 + o];
    feat[((size_t)n * 128 + o) * 20 + t] = s;
  }
}

// ------------- q/k fields, f16, layout [s][n][l][16]; grid (n, chunk) -------------
__global__ __launch_bounds__(256) void qk2_kernel(const float* __restrict__ feat,
                                                  const float* __restrict__ q_w,
                                                  const float* __restrict__ q_b,
                                                  const float* __restrict__ k_w,
                                                  const float* __restrict__ k_b,
                                                  unsigned short* __restrict__ qh,
                                                  unsigned short* __restrict__ kh) {
  int n = blockIdx.x, chunk = blockIdx.y, t = threadIdx.x;
  __shared__ float fL[128 * 20];
  __shared__ float GH[2][16][20];
  for (int idx = t; idx < 2560; idx += 256) fL[idx] = feat[(size_t)n * 2560 + idx];
  __syncthreads();
  for (int idx = t; idx < 640; idx += 256) {
    int which = idx / 320, rem = idx % 320, qc = rem / 20, j = rem % 20;
    const float* w = which ? k_w : q_w;
    float s = which ? k_b[qc] : q_b[qc];
    for (int c = 0; c < 128; ++c) s += w[qc * 128 + c] * fL[c * 20 + j];
    GH[which][qc][j] = s;
  }
  __syncthreads();
  {
    int row = t + 256 * chunk;           // 4096 rows: [s][which][l]
    int l = row & 1023, which = (row >> 10) & 1, s = row >> 11;
    int ry = l >> 5, cx = l & 31;
    int t0, t1, t2, t3;
    float w0, w1, w2, w3;
    if (s == 0) {
      float a = ry * (1.0f / 31.0f), b2 = cx * (1.0f / 31.0f);
      t0 = 0; t1 = 1; t2 = 2; t3 = 3;
      w0 = (1.f - a) * (1.f - b2); w1 = (1.f - a) * b2;
      w2 = a * (1.f - b2);         w3 = a * b2;
    } else {
      float pr = ry * (3.0f / 31.0f);
      int lr = (int)pr; if (lr > 2) lr = 2;
      float fr = pr - (float)lr;
      float pc = cx * (3.0f / 31.0f);
      int lc = (int)pc; if (lc > 2) lc = 2;
      float fc = pc - (float)lc;
      int base = 4 + lr * 4 + lc;
      t0 = base; t1 = base + 1; t2 = base + 4; t3 = base + 5;
      w0 = (1.f - fr) * (1.f - fc); w1 = (1.f - fr) * fc;
      w2 = fr * (1.f - fc);         w3 = fr * fc;
    }
    float val[16];
#pragma unroll
    for (int qc = 0; qc < 16; ++qc) {
      const float* G = GH[which][qc];
      val[qc] = w0 * G[t0] + w1 * G[t1] + w2 * G[t2] + w3 * G[t3];
    }
    unsigned short* dst = (which ? kh : qh) + (((size_t)(s * 16 + n) * 1024 + l) * 16);
#pragma unroll
    for (int u = 0; u < 4; ++u)
      *(ushort4*)(dst + 4 * u) = make_ushort4(f2h(val[4*u]), f2h(val[4*u+1]),
                                              f2h(val[4*u+2]), f2h(val[4*u+3]));
  }
}

// ------------- value-proj GEMM (f16 MFMA) + fused raw-mean accumulation -------------
__global__ __launch_bounds__(256) void pvmm2_kernel(const unsigned short* __restrict__ vwh,
                                                    const unsigned short* __restrict__ xT,
                                                    const float* __restrict__ vb,
                                                    unsigned short* __restrict__ pvh,
                                                    float* __restrict__ means) {
  int l0 = blockIdx.x * 64;
  int n = blockIdx.y;
  int t = threadIdx.x, lane = t & 63, wv = t >> 6;
  int wm = (wv & 1) * 64, wn = (wv >> 1) * 32;

  __shared__ short Asm[128 * 32];
  __shared__ short Bsm[64 * 32];

  int ar0 = t >> 2,        aq0 = (t & 3) ^ ((ar0 >> 1) & 3);
  int idx1 = t + 256; int ar1 = idx1 >> 2, aq1 = (idx1 & 3) ^ ((ar1 >> 1) & 3);
  int br  = t >> 2,        bq  = (t & 3) ^ ((br >> 1) & 3);
  const unsigned short* Ab0 = vwh + (size_t)ar0 * 512 + aq0 * 8;
  const unsigned short* Ab1 = vwh + (size_t)ar1 * 512 + aq1 * 8;
  const unsigned short* Bb  = xT + ((size_t)n * 1024 + l0 + br) * 512 + bq * 8;
  char* ldsA = (char*)Asm;
  char* ldsB = (char*)Bsm;
  int wvoff = wv * 1024;
  int r15 = lane & 15, kg = lane >> 4;
  int kq = kg ^ ((r15 >> 1) & 3);

  f32x4 acc[4][2];
#pragma unroll
  for (int i = 0; i < 4; ++i)
#pragma unroll
    for (int j = 0; j < 2; ++j) acc[i][j] = (f32x4){0.f, 0.f, 0.f, 0.f};

  for (int k0 = 0; k0 < 512; k0 += 32) {
    __syncthreads();
    gload_lds16(Ab0 + k0, ldsA + wvoff);
    gload_lds16(Ab1 + k0, ldsA + 4096 + wvoff);
    gload_lds16(Bb + k0,  ldsB + wvoff);
    __syncthreads();
    f16x8 af[4], bfr[2];
#pragma unroll
    for (int mt2 = 0; mt2 < 4; ++mt2)
      af[mt2] = *(const f16x8*)&Asm[(wm + mt2 * 16 + r15) * 32 + kq * 8];
#pragma unroll
    for (int nt2 = 0; nt2 < 2; ++nt2)
      bfr[nt2] = *(const f16x8*)&Bsm[(wn + nt2 * 16 + r15) * 32 + kq * 8];
#pragma unroll
    for (int mt2 = 0; mt2 < 4; ++mt2)
#pragma unroll
      for (int nt2 = 0; nt2 < 2; ++nt2)
        acc[mt2][nt2] = __builtin_amdgcn_mfma_f32_16x16x32_f16(af[mt2], bfr[nt2], acc[mt2][nt2], 0, 0, 0);
  }

  int c_lo = wm + kg * 4;
  int l_lo = wn + r15;
#pragma unroll
  for (int mt2 = 0; mt2 < 4; ++mt2)
#pragma unroll
    for (int r = 0; r < 4; ++r) {
      int c = c_lo + mt2 * 16 + r;
      float bias = vb[c];
      float v0 = acc[mt2][0][r] + bias;
      float v1 = acc[mt2][1][r] + bias;
      unsigned short* pp = pvh + ((size_t)n * 128 + c) * 1024 + l0 + l_lo;
      pp[0]  = f2h(v0);
      pp[16] = f2h(v1);
      float s = v0 + v1;
      s += __shfl_xor(s, 1); s += __shfl_xor(s, 2);
      s += __shfl_xor(s, 4); s += __shfl_xor(s, 8);
      if (r15 == 0) atomicAdd(&means[n * 128 + c], s);
    }
}

// ---- basecor: cor[n][oc][a*3+b] from raw-sum means (x 1/1024) ----
__global__ __launch_bounds__(64) void basecor_kernel(const float* __restrict__ means,
                                                     const float* __restrict__ fw,
                                                     float* __restrict__ cor) {
  int oc = blockIdx.x, n = blockIdx.y, t = threadIdx.x;
  float S[9];
#pragma unroll
  for (int j = 0; j < 9; ++j) S[j] = 0.f;
  for (int c = t; c < 128; c += 64) {
    float m = means[n * 128 + c] * (1.f / 1024.f);
    const float* wp = fw + (size_t)oc * 3456 + c * 9;
#pragma unroll
    for (int j = 0; j < 9; ++j) S[j] += m * wp[j];
  }
  __shared__ float red[64][9];
  __shared__ float Sf[9];
#pragma unroll
  for (int j = 0; j < 9; ++j) red[t][j] = S[j];
  __syncthreads();
  if (t < 9) {
    float s = 0.f;
    for (int i = 0; i < 64; ++i) s += red[i][t];
    Sf[t] = s;
  }
  __syncthreads();
  if (t < 9) {
    int a = t / 3, b = t % 3;
    float s = 0.f;
#pragma unroll
    for (int ky = 0; ky < 3; ++ky) {
      if ((a == 0 && ky == 0) || (a == 2 && ky == 2)) continue;
#pragma unroll
      for (int kx = 0; kx < 3; ++kx) {
        if ((b == 0 && kx == 0) || (b == 2 && kx == 2)) continue;
        s += Sf[ky * 3 + kx];
      }
    }
    cor[((size_t)n * 512 + oc) * 9 + t] = s;
  }
}

// ------------- fused flash attention (MFMA QK^T + MFMA PV, no P in HBM) -------------
__global__ __launch_bounds__(256) void fattn_kernel(const unsigned short* __restrict__ qh,
                                                    const unsigned short* __restrict__ kh,
                                                    const unsigned short* __restrict__ pvh,
                                                    unsigned short* __restrict__ catp) {
  int m0 = blockIdx.x * 64;
  int n = blockIdx.y, sc = blockIdx.z;
  int t = threadIdx.x, lane = t & 63, wv = t >> 6;
  int wc = (wv >> 1) * 64;
  int wm2 = (wv & 1) * 32;
  int r15 = lane & 15, kg = lane >> 4;
  int kq = kg ^ ((r15 >> 1) & 3);

  const unsigned short* qb  = qh + ((size_t)(sc * 16 + n) * 1024 + m0 + wv * 16) * 16;
  const unsigned short* kb  = kh + ((size_t)(sc * 16 + n) * 1024) * 16;
  const unsigned short* pvb = pvh + (size_t)n * 128 * 1024;

  __shared__ short PVs[2 * 128 * 32];
  __shared__ _Float16 Us[64 * 72];
  __shared__ float rsum[64];

  f16x8 zf = {0, 0, 0, 0, 0, 0, 0, 0};
  f16x8 qa = (kg < 2) ? *(const f16x8*)(qb + r15 * 16 + kg * 8) : zf;

  int prow = t >> 2;
  int aq = (t & 3) ^ ((prow >> 1) & 3);
  const unsigned short* Pb0 = pvb + (size_t)prow * 1024 + aq * 8;
  const unsigned short* Pb1 = pvb + (size_t)(prow + 64) * 1024 + aq * 8;
  char* ldsPV = (char*)PVs;
  int wvoff = wv * 1024;

  f32x4 acc[4][2];
#pragma unroll
  for (int i = 0; i < 4; ++i)
#pragma unroll
    for (int j = 0; j < 2; ++j) acc[i][j] = (f32x4){0.f, 0.f, 0.f, 0.f};
  float rs[4] = {0.f, 0.f, 0.f, 0.f};

  for (int it = 0; it < 16; ++it) {
    int l0 = it * 64;
    __syncthreads();
    gload_lds16(Pb0 + l0,      ldsPV + wvoff);
    gload_lds16(Pb1 + l0,      ldsPV + 4096 + wvoff);
    gload_lds16(Pb0 + l0 + 32, ldsPV + 8192 + wvoff);
    gload_lds16(Pb1 + l0 + 32, ldsPV + 12288 + wvoff);

    f32x4 sacc[4];
#pragma unroll
    for (int lt = 0; lt < 4; ++lt) {
      f16x8 kbf = (kg < 2)
        ? *(const f16x8*)(kb + (size_t)(l0 + lt * 16 + r15) * 16 + kg * 8) : zf;
      sacc[lt] = __builtin_amdgcn_mfma_f32_16x16x32_f16(qa, kbf, (f32x4){0.f,0.f,0.f,0.f}, 0, 0, 0);
    }
#pragma unroll
    for (int lt = 0; lt < 4; ++lt)
#pragma unroll
      for (int r = 0; r < 4; ++r) {
        float e = __expf(sacc[lt][r]);
        Us[(wv * 16 + kg * 4 + r) * 72 + lt * 16 + r15] = (_Float16)e;
        rs[r] += e;
      }
    __syncthreads();

#pragma unroll
    for (int ks = 0; ks < 2; ++ks) {
      f16x8 bfr[2];
#pragma unroll
      for (int nt = 0; nt < 2; ++nt)
        bfr[nt] = *(const f16x8*)&Us[(wm2 + nt * 16 + r15) * 72 + ks * 32 + kg * 8];
#pragma unroll
      for (int ct = 0; ct < 4; ++ct) {
        f16x8 af = *(const f16x8*)&PVs[ks * 4096 + (wc + ct * 16 + r15) * 32 + kq * 8];
#pragma unroll
        for (int nt = 0; nt < 2; ++nt)
          acc[ct][nt] = __builtin_amdgcn_mfma_f32_16x16x32_f16(af, bfr[nt], acc[ct][nt], 0, 0, 0);
      }
    }
  }

#pragma unroll
  for (int r = 0; r < 4; ++r) {
    rs[r] += __shfl_xor(rs[r], 1);
    rs[r] += __shfl_xor(rs[r], 2);
    rs[r] += __shfl_xor(rs[r], 4);
    rs[r] += __shfl_xor(rs[r], 8);
  }
  if (r15 == 0) {
#pragma unroll
    for (int r = 0; r < 4; ++r) rsum[wv * 16 + kg * 4 + r] = rs[r];
  }
  __syncthreads();

#pragma unroll
  for (int nt = 0; nt < 2; ++nt) {
    float inv = 1.f / rsum[wm2 + nt * 16 + r15];
    int pix = m0 + wm2 + nt * 16 + r15;
    unsigned short* ob = catp + ((size_t)n * 1156 + ((pix >> 5) + 1) * 34 + (pix & 31) + 1) * 256
                       + sc * 128 + wc + kg * 4;
#pragma unroll
    for (int ct = 0; ct < 4; ++ct) {
      ushort4 o = make_ushort4(f2bf(acc[ct][nt][0] * inv), f2bf(acc[ct][nt][1] * inv),
                               f2bf(acc[ct][nt][2] * inv), f2bf(acc[ct][nt][3] * inv));
      *(ushort4*)(ob + ct * 16) = o;
    }
  }
}

// ------- fusion conv implicit GEMM (bf16 MFMA, K=2304) + cor + f16-y + fused BN stats -------
__global__ __launch_bounds__(256) void convmm_kernel(const unsigned short* __restrict__ Aw,
                                                     const unsigned short* __restrict__ catp,
                                                     const float* __restrict__ cor,
                                                     unsigned short* __restrict__ yh,
                                                     float* __restrict__ stats) {
  int ntile = blockIdx.x;
  int n = ntile >> 3, y0 = (ntile & 7) * 4;
  int m0 = blockIdx.y * 128;
  int t = threadIdx.x;
  int lane = t & 63, wv = t >> 6;
  int wm = (wv & 1) * 64, wn = (wv >> 1) * 64;

  __shared__ short Asm[128 * 32];
  __shared__ short Bsm[128 * 32];

  int idx0 = t, idx1 = t + 256;
  int ar0 = idx0 >> 2, aq0 = (idx0 & 3) ^ ((ar0 >> 1) & 3);
  int ar1 = idx1 >> 2, aq1 = (idx1 & 3) ^ ((ar1 >> 1) & 3);
  size_t abase0 = (size_t)(m0 + ar0) * 2304 + aq0 * 8;
  size_t abase1 = (size_t)(m0 + ar1) * 2304 + aq1 * 8;
  size_t bbase0 = ((size_t)n * 1156 + (size_t)(y0 + (ar0 >> 5)) * 34 + (ar0 & 31)) * 256 + aq0 * 8;
  size_t bbase1 = ((size_t)n * 1156 + (size_t)(y0 + (ar1 >> 5)) * 34 + (ar1 & 31)) * 256 + aq1 * 8;
  char* ldsA = (char*)Asm;
  char* ldsB = (char*)Bsm;
  int wvoff = wv * 1024;

  int r15 = lane & 15, kg = lane >> 4;
  int kq = kg ^ ((r15 >> 1) & 3);

  f32x4 acc[4][4];
#pragma unroll
  for (int i = 0; i < 4; ++i)
#pragma unroll
    for (int j = 0; j < 4; ++j) acc[i][j] = (f32x4){0.f, 0.f, 0.f, 0.f};

  for (int seg = 0; seg < 9; ++seg) {
    size_t boffseg = (size_t)((seg / 3) * 34 + (seg % 3)) * 256;
    size_t akkseg = (size_t)seg * 256;
    for (int icc = 0; icc < 8; ++icc) {
      size_t akk = akkseg + icc * 32;
      size_t boff = boffseg + icc * 32;
      __syncthreads();
      gload_lds16(Aw + abase0 + akk,   ldsA + wvoff);
      gload_lds16(Aw + abase1 + akk,   ldsA + 4096 + wvoff);
      gload_lds16(catp + bbase0 + boff, ldsB + wvoff);
      gload_lds16(catp + bbase1 + boff, ldsB + 4096 + wvoff);
      __syncthreads();
      bf16x8 af[4], bf[4];
#pragma unroll
      for (int mt = 0; mt < 4; ++mt)
        af[mt] = *(const bf16x8*)&Asm[(wm + mt * 16 + r15) * 32 + kq * 8];
#pragma unroll
      for (int nt = 0; nt < 4; ++nt)
        bf[nt] = *(const bf16x8*)&Bsm[(wn + nt * 16 + r15) * 32 + kq * 8];
#pragma unroll
      for (int mt = 0; mt < 4; ++mt)
#pragma unroll
        for (int nt = 0; nt < 4; ++nt)
          acc[mt][nt] = __builtin_amdgcn_mfma_f32_16x16x32_bf16(af[mt], bf[nt], acc[mt][nt], 0, 0, 0);
    }
  }

  // epilogue: y = acc + cor (f16 store) + per-channel sum/sumsq -> atomics
  int pixbase = (ntile & 7) * 128 + wn + r15;
  int ocb = m0 + wm + kg * 4;
#pragma unroll
  for (int mt = 0; mt < 4; ++mt)
#pragma unroll
    for (int r = 0; r < 4; ++r) {
      int oc = ocb + mt * 16 + r;
      const float* cp = cor + ((size_t)n * 512 + oc) * 9;
      unsigned short* yp = yh + ((size_t)n * 512 + oc) * 1024;
      float s = 0.f, q = 0.f;
#pragma unroll
      for (int nt = 0; nt < 4; ++nt) {
        int pix = pixbase + nt * 16;
        int py = pix >> 5, px = pix & 31;
        int yc = (py == 0) ? 0 : ((py == 31) ? 2 : 1);
        int xc = (px == 0) ? 0 : ((px == 31) ? 2 : 1);
        float yv = acc[mt][nt][r] + cp[yc * 3 + xc];
        yp[pix] = f2h(yv);
        s += yv;
        q += yv * yv;
      }
      s += __shfl_xor(s, 1); s += __shfl_xor(s, 2);
      s += __shfl_xor(s, 4); s += __shfl_xor(s, 8);
      q += __shfl_xor(q, 1); q += __shfl_xor(q, 2);
      q += __shfl_xor(q, 4); q += __shfl_xor(q, 8);
      if (r15 == 0) {
        atomicAdd(&stats[oc], s);
        atomicAdd(&stats[512 + oc], q);
      }
    }
}

// ---------------- finalize: BN from raw sums + relu + gamma*y + x ----------------
__global__ __launch_bounds__(256) void final_kernel(const unsigned short* __restrict__ yh,
                                                    const float* __restrict__ x,
                                                    const float* __restrict__ stats,
                                                    const float* __restrict__ bn_scale,
                                                    const float* __restrict__ bn_bias,
                                                    const float* __restrict__ gamma,
                                                    float* __restrict__ outp) {
  int b = blockIdx.x;
  int c = b & 511;
  int t = threadIdx.x;
  float sum = stats[c], sq = stats[512 + c];
  float mean = sum * (1.f / 16384.f);
  float var = sq * (1.f / 16384.f) - mean * mean;
  float se = bn_scale[c] / sqrtf(var + 1e-5f);
  float sh = bn_bias[c] - mean * se;
  float g = gamma[0];
  f16x4 yv = ((const f16x4*)(yh + (size_t)b * 1024))[t];
  float4 xv = ((const float4*)(x + (size_t)b * 1024))[t];
  float4 o;
  o.x = g * fmaxf((float)yv[0] * se + sh, 0.f) + xv.x;
  o.y = g * fmaxf((float)yv[1] * se + sh, 0.f) + xv.y;
  o.z = g * fmaxf((float)yv[2] * se + sh, 0.f) + xv.z;
  o.w = g * fmaxf((float)yv[3] * se + sh, 0.f) + xv.w;
  ((float4*)(outp + (size_t)b * 1024))[t] = o;
}

extern "C" void kernel_launch(void* const* d_in, const int* in_sizes, int n_in,
                              void* d_out, int out_size, void* d_ws, size_t ws_size,
                              hipStream_t stream) {
  const float* x        = (const float*)d_in[0];
  const float* rce_w    = (const float*)d_in[1];
  const float* rce_b    = (const float*)d_in[2];
  const float* q_w      = (const float*)d_in[3];
  const float* q_b      = (const float*)d_in[4];
  const float* k_w      = (const float*)d_in[5];
  const float* k_b      = (const float*)d_in[6];
  const float* value_w  = (const float*)d_in[7];
  const float* value_b  = (const float*)d_in[8];
  const float* fw       = (const float*)d_in[9];
  const float* bn_scale = (const float*)d_in[10];
  const float* bn_bias  = (const float*)d_in[11];
  const float* gamma    = (const float*)d_in[12];

  float* ws    = (float*)d_ws;
  float* cor   = ws + OFF_COR;
  unsigned short* pvh = (unsigned short*)(ws + OFF_PVH);
  unsigned short* yh    = (unsigned short*)(ws + OFF_Y);
  unsigned short* xTbuf = (unsigned short*)(ws + OFF_Y);  // union: dead before convmm
  unsigned short* catp = (unsigned short*)(ws + OFF_CATP);
  unsigned short* qh   = (unsigned short*)(ws + OFF_QH);
  unsigned short* kh   = (unsigned short*)(ws + OFF_KH);
  float* pool  = ws + OFF_POOL;
  float* feat  = ws + OFF_FEAT;
  unsigned short* Aw = (unsigned short*)(ws + OFF_AW);
  float* means = ws + OFF_MEANS;
  float* stats = ws + OFF_STAT;
  unsigned short* vwh = (unsigned short*)(ws + OFF_VWH);
  float* outp  = (float*)d_out;

  hipLaunchKernelGGL(prep_kernel,    dim3(12065),      dim3(256), 0, stream,
                     x, value_w, fw, pool, xTbuf, vwh, Aw, catp, stats, means);
  hipLaunchKernelGGL(feat_kernel,    dim3(128, 16),    dim3(64),  0, stream, pool, rce_w, rce_b, feat);
  hipLaunchKernelGGL(qk2_kernel,     dim3(16, 16),     dim3(256), 0, stream, feat, q_w, q_b, k_w, k_b, qh, kh);
  hipLaunchKernelGGL(pvmm2_kernel,   dim3(16, 16),     dim3(256), 0, stream, vwh, xTbuf, value_b, pvh, means);
  hipLaunchKernelGGL(basecor_kernel, dim3(512, 16),    dim3(64),  0, stream, means, fw, cor);
  hipLaunchKernelGGL(fattn_kernel,   dim3(16, 16, 2),  dim3(256), 0, stream, qh, kh, pvh, catp);
  hipLaunchKernelGGL(convmm_kernel,  dim3(128, 4),     dim3(256), 0, stream, Aw, catp, cor, yh, stats);
  hipLaunchKernelGGL(final_kernel,   dim3(8192),       dim3(256), 0, stream,
                     yh, x, stats, bn_scale, bn_bias, gamma, outp);
}